// Round 1
// baseline (1310.449 us; speedup 1.0000x reference)
//
#include <hip/hip_runtime.h>
#include <math.h>

// Problem constants (reference: N_NODES=50000, F_in=1433, F1=16, F2=7)
#define F_IN 1433
#define F1 16
#define F2 7
#define KC 32          // K-chunk for gemm1
#define G1_ROWS 128    // rows per block in gemm1
#define SCAN_CHUNK 2048

// ---------------- init ----------------
__global__ void k_init_cnt(int* __restrict__ cnt, int N) {
    int i = blockIdx.x * 256 + threadIdx.x;
    if (i < N) cnt[i] = 0;
}

// ---------------- degree count ----------------
__global__ void k_count(const int* __restrict__ edges, int* __restrict__ cnt, int E) {
    int e = blockIdx.x * 256 + threadIdx.x;
    if (e < E) atomicAdd(&cnt[edges[E + e]], 1);   // dst = edges[E + e]
}

// ---------------- scan (3-phase exclusive prefix over cnt -> row_start) ------
__global__ void k_scan1(const int* __restrict__ cnt, int* __restrict__ rs,
                        int* __restrict__ bsum, int N) {
    __shared__ int sh[256];
    int tid = threadIdx.x;
    int base = blockIdx.x * SCAN_CHUNK + tid * 8;
    int v[8];
    int s = 0;
#pragma unroll
    for (int u = 0; u < 8; ++u) {
        int idx = base + u;
        v[u] = (idx < N) ? cnt[idx] : 0;
        s += v[u];
    }
    sh[tid] = s;
    __syncthreads();
    // Hillis-Steele inclusive scan over 256 thread sums
    for (int off = 1; off < 256; off <<= 1) {
        int y = 0;
        if (tid >= off) y = sh[tid - off];
        __syncthreads();
        sh[tid] += y;
        __syncthreads();
    }
    int run = sh[tid] - s;   // exclusive prefix for this thread's chunk
#pragma unroll
    for (int u = 0; u < 8; ++u) {
        int idx = base + u;
        if (idx < N) rs[idx] = run;
        run += v[u];
    }
    if (tid == 255) bsum[blockIdx.x] = sh[255];
}

__global__ void k_scan2(const int* __restrict__ bsum, int* __restrict__ boff, int NB) {
    if (blockIdx.x == 0 && threadIdx.x == 0) {
        int r = 0;
        for (int b = 0; b < NB; ++b) { int t = bsum[b]; boff[b] = r; r += t; }
    }
}

__global__ void k_scan3(int* __restrict__ rs, int* __restrict__ cursor,
                        const int* __restrict__ cnt, float* __restrict__ dinv,
                        const int* __restrict__ boff, int N) {
    int i = blockIdx.x * 256 + threadIdx.x;
    if (i < N) {
        int r = rs[i] + boff[i / SCAN_CHUNK];
        rs[i] = r;
        cursor[i] = r;
        dinv[i] = rsqrtf((float)cnt[i] + 1.0f);   // +1 self loop
    }
}

// ---------------- CSR fill ----------------
__global__ void k_fill(const int* __restrict__ edges, int* __restrict__ cursor,
                       int* __restrict__ col, int E) {
    int e = blockIdx.x * 256 + threadIdx.x;
    if (e < E) {
        int d = edges[E + e];
        int s = edges[e];
        int pos = atomicAdd(&cursor[d], 1);
        col[pos] = s;
    }
}

// ---------------- GEMM1: g = dinv[row] * (x @ W1) ----------------
__global__ __launch_bounds__(G1_ROWS) void k_gemm1(const float* __restrict__ x,
                                                   const float* __restrict__ W,
                                                   const float* __restrict__ dinv,
                                                   float* __restrict__ g, int N) {
    __shared__ float xs[G1_ROWS * 33];  // stride 33: conflict-free
    int tid = threadIdx.x;
    int r0 = blockIdx.x * G1_ROWS;
    float acc[F1];
#pragma unroll
    for (int j = 0; j < F1; ++j) acc[j] = 0.f;
    int colId = tid & 31;   // 0..31
    int rowq = tid >> 5;    // 0..3

    for (int k0 = 0; k0 < F_IN; k0 += KC) {
        __syncthreads();
        // stage G1_ROWS x KC tile, coalesced
#pragma unroll
        for (int p = 0; p < G1_ROWS / 4; ++p) {
            int row = p * 4 + rowq;
            int gr = r0 + row;
            int k = k0 + colId;
            float v = 0.f;
            if (gr < N && k < F_IN) v = x[(long)gr * F_IN + k];
            xs[row * 33 + colId] = v;
        }
        __syncthreads();
#pragma unroll
        for (int kk = 0; kk < KC; ++kk) {
            if (k0 + kk < F_IN) {
                float xv = xs[tid * 33 + kk];
                const float4* w4 = (const float4*)(W + (long)(k0 + kk) * F1);
                float4 wa = w4[0], wb = w4[1], wc = w4[2], wd = w4[3];
                acc[0]  = fmaf(xv, wa.x, acc[0]);
                acc[1]  = fmaf(xv, wa.y, acc[1]);
                acc[2]  = fmaf(xv, wa.z, acc[2]);
                acc[3]  = fmaf(xv, wa.w, acc[3]);
                acc[4]  = fmaf(xv, wb.x, acc[4]);
                acc[5]  = fmaf(xv, wb.y, acc[5]);
                acc[6]  = fmaf(xv, wb.z, acc[6]);
                acc[7]  = fmaf(xv, wb.w, acc[7]);
                acc[8]  = fmaf(xv, wc.x, acc[8]);
                acc[9]  = fmaf(xv, wc.y, acc[9]);
                acc[10] = fmaf(xv, wc.z, acc[10]);
                acc[11] = fmaf(xv, wc.w, acc[11]);
                acc[12] = fmaf(xv, wd.x, acc[12]);
                acc[13] = fmaf(xv, wd.y, acc[13]);
                acc[14] = fmaf(xv, wd.z, acc[14]);
                acc[15] = fmaf(xv, wd.w, acc[15]);
            }
        }
    }
    int gr = r0 + tid;
    if (gr < N) {
        float d = dinv[gr];
        float4* out = (float4*)(g + (long)gr * F1);
        float4 o;
        o.x = d * acc[0];  o.y = d * acc[1];  o.z = d * acc[2];  o.w = d * acc[3];
        out[0] = o;
        o.x = d * acc[4];  o.y = d * acc[5];  o.z = d * acc[6];  o.w = d * acc[7];
        out[1] = o;
        o.x = d * acc[8];  o.y = d * acc[9];  o.z = d * acc[10]; o.w = d * acc[11];
        out[2] = o;
        o.x = d * acc[12]; o.y = d * acc[13]; o.z = d * acc[14]; o.w = d * acc[15];
        out[3] = o;
    }
}

// ---------------- gather layer1: x1 = relu(dinv*(sum g[src] + g[self]) + b1) --
__global__ __launch_bounds__(256) void k_gather1(const int* __restrict__ col,
                                                 const int* __restrict__ rs,
                                                 const int* __restrict__ cnt,
                                                 const float* __restrict__ g,
                                                 const float* __restrict__ dinv,
                                                 const float* __restrict__ b1,
                                                 float* __restrict__ x1, int N) {
    int node = blockIdx.x * 4 + (threadIdx.x >> 6);
    if (node >= N) return;
    int lane = threadIdx.x & 63;
    int q = lane >> 4;   // neighbor slot 0..3
    int j = lane & 15;   // feature
    int start = rs[node];
    int c = cnt[node];
    float acc = 0.f;
    for (int p = q; p < c; p += 4) {
        int s = col[start + p];
        acc += g[(long)s * F1 + j];
    }
    acc += __shfl_down(acc, 32, 64);
    acc += __shfl_down(acc, 16, 64);
    if (lane < 16) {
        float v = dinv[node] * (acc + g[(long)node * F1 + j]) + b1[j];
        x1[(long)node * F1 + j] = fmaxf(v, 0.f);
    }
}

// ---------------- GEMM2: g2 = dinv * (x1 @ W2), padded to 8 cols -------------
__global__ __launch_bounds__(256) void k_gemm2(const float* __restrict__ x1,
                                               const float* __restrict__ W2,
                                               const float* __restrict__ dinv,
                                               float* __restrict__ g2, int N) {
    int i = blockIdx.x * 256 + threadIdx.x;
    if (i >= N) return;
    const float4* xr = (const float4*)(x1 + (long)i * F1);
    float4 a0 = xr[0], a1 = xr[1], a2 = xr[2], a3 = xr[3];
    float xv[F1] = {a0.x, a0.y, a0.z, a0.w, a1.x, a1.y, a1.z, a1.w,
                    a2.x, a2.y, a2.z, a2.w, a3.x, a3.y, a3.z, a3.w};
    float acc[F2];
#pragma unroll
    for (int j = 0; j < F2; ++j) acc[j] = 0.f;
#pragma unroll
    for (int k = 0; k < F1; ++k) {
#pragma unroll
        for (int j = 0; j < F2; ++j) acc[j] = fmaf(xv[k], W2[k * F2 + j], acc[j]);
    }
    float d = dinv[i];
    float4* out = (float4*)(g2 + (long)i * 8);
    float4 o;
    o.x = d * acc[0]; o.y = d * acc[1]; o.z = d * acc[2]; o.w = d * acc[3];
    out[0] = o;
    o.x = d * acc[4]; o.y = d * acc[5]; o.z = d * acc[6]; o.w = 0.f;
    out[1] = o;
}

// ---------------- gather layer2 + bias + log_softmax -> d_out ----------------
__global__ __launch_bounds__(256) void k_gather2(const int* __restrict__ col,
                                                 const int* __restrict__ rs,
                                                 const int* __restrict__ cnt,
                                                 const float* __restrict__ g2,
                                                 const float* __restrict__ dinv,
                                                 const float* __restrict__ b2,
                                                 float* __restrict__ out, int N) {
    int node = blockIdx.x * 4 + (threadIdx.x >> 6);
    if (node >= N) return;
    int lane = threadIdx.x & 63;
    int q = lane >> 3;  // neighbor slot 0..7
    int j = lane & 7;   // feature 0..7 (7 = pad)
    int start = rs[node];
    int c = cnt[node];
    float acc = 0.f;
    for (int p = q; p < c; p += 8) {
        int s = col[start + p];
        acc += g2[(long)s * 8 + j];
    }
    acc += __shfl_down(acc, 32, 64);
    acc += __shfl_down(acc, 16, 64);
    acc += __shfl_down(acc, 8, 64);
    if (lane < 8) {
        float vv = -INFINITY;
        if (j < F2)
            vv = dinv[node] * (acc + g2[(long)node * 8 + j]) + b2[j];
        // max over 8 lanes (butterfly within lanes 0..7)
        float m = vv;
        m = fmaxf(m, __shfl_xor(m, 1, 64));
        m = fmaxf(m, __shfl_xor(m, 2, 64));
        m = fmaxf(m, __shfl_xor(m, 4, 64));
        float e = (j < F2) ? expf(vv - m) : 0.f;
        e += __shfl_xor(e, 1, 64);
        e += __shfl_xor(e, 2, 64);
        e += __shfl_xor(e, 4, 64);
        if (j < F2)
            out[(long)node * F2 + j] = vv - m - logf(e);
    }
}

extern "C" void kernel_launch(void* const* d_in, const int* in_sizes, int n_in,
                              void* d_out, int out_size, void* d_ws, size_t ws_size,
                              hipStream_t stream) {
    const float* x     = (const float*)d_in[0];
    const int*   edges = (const int*)d_in[1];
    const float* W1    = (const float*)d_in[2];
    const float* b1    = (const float*)d_in[3];
    const float* W2    = (const float*)d_in[4];
    const float* b2    = (const float*)d_in[5];
    float* outp = (float*)d_out;

    int N = in_sizes[0] / F_IN;       // 50000
    int E = in_sizes[1] / 2;          // 1600000
    int NB = (N + SCAN_CHUNK - 1) / SCAN_CHUNK;

    // workspace layout (256B-aligned slices)
    char* ws = (char*)d_ws;
    size_t o = 0;
    auto alloc = [&](size_t bytes) { size_t r = o; o += (bytes + 255) & ~(size_t)255; return r; };
    int*   cnt    = (int*)  (ws + alloc((size_t)N * 4));
    int*   rs     = (int*)  (ws + alloc((size_t)N * 4));
    int*   cursor = (int*)  (ws + alloc((size_t)N * 4));
    float* dinv   = (float*)(ws + alloc((size_t)N * 4));
    int*   bsum   = (int*)  (ws + alloc((size_t)NB * 4));
    int*   boff   = (int*)  (ws + alloc((size_t)NB * 4));
    int*   col    = (int*)  (ws + alloc((size_t)E * 4));
    float* g      = (float*)(ws + alloc((size_t)N * F1 * 4));
    float* x1     = (float*)(ws + alloc((size_t)N * F1 * 4));
    float* g2     = (float*)(ws + alloc((size_t)N * 8 * 4));
    (void)ws_size; (void)n_in; (void)out_size;

    int gN256 = (N + 255) / 256;
    int gE256 = (E + 255) / 256;

    k_init_cnt<<<gN256, 256, 0, stream>>>(cnt, N);
    k_count<<<gE256, 256, 0, stream>>>(edges, cnt, E);
    k_scan1<<<NB, 256, 0, stream>>>(cnt, rs, bsum, N);
    k_scan2<<<1, 64, 0, stream>>>(bsum, boff, NB);
    k_scan3<<<gN256, 256, 0, stream>>>(rs, cursor, cnt, dinv, boff, N);
    k_fill<<<gE256, 256, 0, stream>>>(edges, cursor, col, E);

    k_gemm1<<<(N + G1_ROWS - 1) / G1_ROWS, G1_ROWS, 0, stream>>>(x, W1, dinv, g, N);
    k_gather1<<<(N + 3) / 4, 256, 0, stream>>>(col, rs, cnt, g, dinv, b1, x1, N);
    k_gemm2<<<gN256, 256, 0, stream>>>(x1, W2, dinv, g2, N);
    k_gather2<<<(N + 3) / 4, 256, 0, stream>>>(col, rs, cnt, g2, dinv, b2, outp, N);
}

// Round 2
// 1012.994 us; speedup vs baseline: 1.2936x; 1.2936x over previous
//
#include <hip/hip_runtime.h>
#include <math.h>

// Problem constants (reference: N_NODES=50000, F_in=1433, F1=16, F2=7)
#define F_IN 1433
#define F1 16
#define F2 7
#define G1_ROWS 128    // rows per block in gemm1
#define KSEG 160       // K per segment (9 segments cover 1440 >= 1433)
#define NSEG 9
#define SCAN_CHUNK 2048

// ---------------- init ----------------
__global__ void k_init_cnt(int* __restrict__ cnt, int N) {
    int i = blockIdx.x * 256 + threadIdx.x;
    if (i < N) cnt[i] = 0;
}

// ---------------- degree count ----------------
__global__ void k_count(const int* __restrict__ edges, int* __restrict__ cnt, int E) {
    int e = blockIdx.x * 256 + threadIdx.x;
    if (e < E) atomicAdd(&cnt[edges[E + e]], 1);   // dst = edges[E + e]
}

// ---------------- scan (3-phase exclusive prefix over cnt -> row_start) ------
__global__ void k_scan1(const int* __restrict__ cnt, int* __restrict__ rs,
                        int* __restrict__ bsum, int N) {
    __shared__ int sh[256];
    int tid = threadIdx.x;
    int base = blockIdx.x * SCAN_CHUNK + tid * 8;
    int v[8];
    int s = 0;
#pragma unroll
    for (int u = 0; u < 8; ++u) {
        int idx = base + u;
        v[u] = (idx < N) ? cnt[idx] : 0;
        s += v[u];
    }
    sh[tid] = s;
    __syncthreads();
    for (int off = 1; off < 256; off <<= 1) {
        int y = 0;
        if (tid >= off) y = sh[tid - off];
        __syncthreads();
        sh[tid] += y;
        __syncthreads();
    }
    int run = sh[tid] - s;
#pragma unroll
    for (int u = 0; u < 8; ++u) {
        int idx = base + u;
        if (idx < N) rs[idx] = run;
        run += v[u];
    }
    if (tid == 255) bsum[blockIdx.x] = sh[255];
}

__global__ void k_scan2(const int* __restrict__ bsum, int* __restrict__ boff, int NB) {
    if (blockIdx.x == 0 && threadIdx.x == 0) {
        int r = 0;
        for (int b = 0; b < NB; ++b) { int t = bsum[b]; boff[b] = r; r += t; }
    }
}

__global__ void k_scan3(int* __restrict__ rs, int* __restrict__ cursor,
                        const int* __restrict__ cnt, float* __restrict__ dinv,
                        const int* __restrict__ boff, int N) {
    int i = blockIdx.x * 256 + threadIdx.x;
    if (i < N) {
        int r = rs[i] + boff[i / SCAN_CHUNK];
        rs[i] = r;
        cursor[i] = r;
        dinv[i] = rsqrtf((float)cnt[i] + 1.0f);   // +1 self loop
    }
}

// ---------------- CSR fill ----------------
__global__ void k_fill(const int* __restrict__ edges, int* __restrict__ cursor,
                       int* __restrict__ col, int E) {
    int e = blockIdx.x * 256 + threadIdx.x;
    if (e < E) {
        int d = edges[E + e];
        int s = edges[e];
        int pos = atomicAdd(&cursor[d], 1);
        col[pos] = s;
    }
}

// ---------------- GEMM1 split-K: gpart[seg] = x[:, seg*160:+160] @ W[...] ----
__global__ __launch_bounds__(G1_ROWS) void k_gemm1(const float* __restrict__ x,
                                                   const float* __restrict__ W,
                                                   float* __restrict__ gpart, int N) {
    __shared__ float xs[G1_ROWS * 33];  // stride 33: conflict-free
    int tid = threadIdx.x;
    int r0 = blockIdx.x * G1_ROWS;
    int k0base = blockIdx.y * KSEG;
    float acc[F1];
#pragma unroll
    for (int j = 0; j < F1; ++j) acc[j] = 0.f;
    int colId = tid & 31;
    int rowq = tid >> 5;

#pragma unroll
    for (int c = 0; c < KSEG / 32; ++c) {
        int k0 = k0base + c * 32;
        __syncthreads();
        // stage G1_ROWS x 32 tile, coalesced, zero-filled out of range
#pragma unroll
        for (int p = 0; p < G1_ROWS / 4; ++p) {
            int row = p * 4 + rowq;
            int gr = r0 + row;
            int k = k0 + colId;
            float v = 0.f;
            if (gr < N && k < F_IN) v = x[(long)gr * F_IN + k];
            xs[row * 33 + colId] = v;
        }
        __syncthreads();
#pragma unroll
        for (int kk = 0; kk < 32; ++kk) {
            float xv = xs[tid * 33 + kk];
            int kw = k0 + kk;
            if (kw > F_IN - 1) kw = F_IN - 1;   // uniform clamp; xv==0 there
            const float4* w4 = (const float4*)(W + (long)kw * F1);
            float4 wa = w4[0], wb = w4[1], wc = w4[2], wd = w4[3];
            acc[0]  = fmaf(xv, wa.x, acc[0]);
            acc[1]  = fmaf(xv, wa.y, acc[1]);
            acc[2]  = fmaf(xv, wa.z, acc[2]);
            acc[3]  = fmaf(xv, wa.w, acc[3]);
            acc[4]  = fmaf(xv, wb.x, acc[4]);
            acc[5]  = fmaf(xv, wb.y, acc[5]);
            acc[6]  = fmaf(xv, wb.z, acc[6]);
            acc[7]  = fmaf(xv, wb.w, acc[7]);
            acc[8]  = fmaf(xv, wc.x, acc[8]);
            acc[9]  = fmaf(xv, wc.y, acc[9]);
            acc[10] = fmaf(xv, wc.z, acc[10]);
            acc[11] = fmaf(xv, wc.w, acc[11]);
            acc[12] = fmaf(xv, wd.x, acc[12]);
            acc[13] = fmaf(xv, wd.y, acc[13]);
            acc[14] = fmaf(xv, wd.z, acc[14]);
            acc[15] = fmaf(xv, wd.w, acc[15]);
        }
    }
    int gr = r0 + tid;
    if (gr < N) {
        float4* out = (float4*)(gpart + ((long)blockIdx.y * N + gr) * F1);
        out[0] = make_float4(acc[0],  acc[1],  acc[2],  acc[3]);
        out[1] = make_float4(acc[4],  acc[5],  acc[6],  acc[7]);
        out[2] = make_float4(acc[8],  acc[9],  acc[10], acc[11]);
        out[3] = make_float4(acc[12], acc[13], acc[14], acc[15]);
    }
}

// ---------------- reduce partials: g = dinv[row] * sum_seg gpart -------------
__global__ __launch_bounds__(256) void k_greduce(const float* __restrict__ gpart,
                                                 const float* __restrict__ dinv,
                                                 float* __restrict__ g, int N) {
    int i4 = blockIdx.x * 256 + threadIdx.x;   // index over N*4 float4s
    if (i4 >= N * 4) return;
    const float4* gp = (const float4*)gpart;
    float4 s = gp[i4];
#pragma unroll
    for (int p = 1; p < NSEG; ++p) {
        float4 t = gp[(long)p * N * 4 + i4];
        s.x += t.x; s.y += t.y; s.z += t.z; s.w += t.w;
    }
    float d = dinv[i4 >> 2];
    s.x *= d; s.y *= d; s.z *= d; s.w *= d;
    ((float4*)g)[i4] = s;
}

// ---------------- gather layer1: x1 = relu(dinv*(sum g[src] + g[self]) + b1) --
__global__ __launch_bounds__(256) void k_gather1(const int* __restrict__ col,
                                                 const int* __restrict__ rs,
                                                 const int* __restrict__ cnt,
                                                 const float* __restrict__ g,
                                                 const float* __restrict__ dinv,
                                                 const float* __restrict__ b1,
                                                 float* __restrict__ x1, int N) {
    int node = blockIdx.x * 4 + (threadIdx.x >> 6);
    if (node >= N) return;
    int lane = threadIdx.x & 63;
    int q = lane >> 4;   // neighbor slot 0..3
    int j = lane & 15;   // feature
    int start = rs[node];
    int c = cnt[node];
    float acc = 0.f;
    for (int p = q; p < c; p += 4) {
        int s = col[start + p];
        acc += g[(long)s * F1 + j];
    }
    acc += __shfl_down(acc, 32, 64);
    acc += __shfl_down(acc, 16, 64);
    if (lane < 16) {
        float v = dinv[node] * (acc + g[(long)node * F1 + j]) + b1[j];
        x1[(long)node * F1 + j] = fmaxf(v, 0.f);
    }
}

// ---------------- GEMM2: g2 = dinv * (x1 @ W2), padded to 8 cols -------------
__global__ __launch_bounds__(256) void k_gemm2(const float* __restrict__ x1,
                                               const float* __restrict__ W2,
                                               const float* __restrict__ dinv,
                                               float* __restrict__ g2, int N) {
    int i = blockIdx.x * 256 + threadIdx.x;
    if (i >= N) return;
    const float4* xr = (const float4*)(x1 + (long)i * F1);
    float4 a0 = xr[0], a1 = xr[1], a2 = xr[2], a3 = xr[3];
    float xv[F1] = {a0.x, a0.y, a0.z, a0.w, a1.x, a1.y, a1.z, a1.w,
                    a2.x, a2.y, a2.z, a2.w, a3.x, a3.y, a3.z, a3.w};
    float acc[F2];
#pragma unroll
    for (int j = 0; j < F2; ++j) acc[j] = 0.f;
#pragma unroll
    for (int k = 0; k < F1; ++k) {
#pragma unroll
        for (int j = 0; j < F2; ++j) acc[j] = fmaf(xv[k], W2[k * F2 + j], acc[j]);
    }
    float d = dinv[i];
    float4* out = (float4*)(g2 + (long)i * 8);
    out[0] = make_float4(d * acc[0], d * acc[1], d * acc[2], d * acc[3]);
    out[1] = make_float4(d * acc[4], d * acc[5], d * acc[6], 0.f);
}

// ---------------- gather layer2 + bias + log_softmax -> d_out ----------------
__global__ __launch_bounds__(256) void k_gather2(const int* __restrict__ col,
                                                 const int* __restrict__ rs,
                                                 const int* __restrict__ cnt,
                                                 const float* __restrict__ g2,
                                                 const float* __restrict__ dinv,
                                                 const float* __restrict__ b2,
                                                 float* __restrict__ out, int N) {
    int node = blockIdx.x * 4 + (threadIdx.x >> 6);
    if (node >= N) return;
    int lane = threadIdx.x & 63;
    int q = lane >> 3;  // neighbor slot 0..7
    int j = lane & 7;   // feature 0..7 (7 = pad)
    int start = rs[node];
    int c = cnt[node];
    float acc = 0.f;
    for (int p = q; p < c; p += 8) {
        int s = col[start + p];
        acc += g2[(long)s * 8 + j];
    }
    acc += __shfl_down(acc, 32, 64);
    acc += __shfl_down(acc, 16, 64);
    acc += __shfl_down(acc, 8, 64);
    if (lane < 8) {
        float vv = -INFINITY;
        if (j < F2)
            vv = dinv[node] * (acc + g2[(long)node * 8 + j]) + b2[j];
        float m = vv;
        m = fmaxf(m, __shfl_xor(m, 1, 64));
        m = fmaxf(m, __shfl_xor(m, 2, 64));
        m = fmaxf(m, __shfl_xor(m, 4, 64));
        float e = (j < F2) ? expf(vv - m) : 0.f;
        e += __shfl_xor(e, 1, 64);
        e += __shfl_xor(e, 2, 64);
        e += __shfl_xor(e, 4, 64);
        if (j < F2)
            out[(long)node * F2 + j] = vv - m - logf(e);
    }
}

extern "C" void kernel_launch(void* const* d_in, const int* in_sizes, int n_in,
                              void* d_out, int out_size, void* d_ws, size_t ws_size,
                              hipStream_t stream) {
    const float* x     = (const float*)d_in[0];
    const int*   edges = (const int*)d_in[1];
    const float* W1    = (const float*)d_in[2];
    const float* b1    = (const float*)d_in[3];
    const float* W2    = (const float*)d_in[4];
    const float* b2    = (const float*)d_in[5];
    float* outp = (float*)d_out;

    int N = in_sizes[0] / F_IN;       // 50000
    int E = in_sizes[1] / 2;          // 1600000
    int NB = (N + SCAN_CHUNK - 1) / SCAN_CHUNK;

    char* ws = (char*)d_ws;
    size_t o = 0;
    auto alloc = [&](size_t bytes) { size_t r = o; o += (bytes + 255) & ~(size_t)255; return r; };
    int*   cnt    = (int*)  (ws + alloc((size_t)N * 4));
    int*   rs     = (int*)  (ws + alloc((size_t)N * 4));
    int*   cursor = (int*)  (ws + alloc((size_t)N * 4));
    float* dinv   = (float*)(ws + alloc((size_t)N * 4));
    int*   bsum   = (int*)  (ws + alloc((size_t)NB * 4));
    int*   boff   = (int*)  (ws + alloc((size_t)NB * 4));
    int*   col    = (int*)  (ws + alloc((size_t)E * 4));
    float* g      = (float*)(ws + alloc((size_t)N * F1 * 4));
    float* x1     = (float*)(ws + alloc((size_t)N * F1 * 4));
    float* g2     = (float*)(ws + alloc((size_t)N * 8 * 4));
    float* gpart  = (float*)(ws + alloc((size_t)NSEG * N * F1 * 4));  // 28.8 MB
    (void)ws_size; (void)n_in; (void)out_size;

    int gN256 = (N + 255) / 256;
    int gE256 = (E + 255) / 256;

    k_init_cnt<<<gN256, 256, 0, stream>>>(cnt, N);
    k_count<<<gE256, 256, 0, stream>>>(edges, cnt, E);
    k_scan1<<<NB, 256, 0, stream>>>(cnt, rs, bsum, N);
    k_scan2<<<1, 64, 0, stream>>>(bsum, boff, NB);
    k_scan3<<<gN256, 256, 0, stream>>>(rs, cursor, cnt, dinv, boff, N);
    k_fill<<<gE256, 256, 0, stream>>>(edges, cursor, col, E);

    dim3 g1grid((N + G1_ROWS - 1) / G1_ROWS, NSEG);
    k_gemm1<<<g1grid, G1_ROWS, 0, stream>>>(x, W1, gpart, N);
    k_greduce<<<(N * 4 + 255) / 256, 256, 0, stream>>>(gpart, dinv, g, N);
    k_gather1<<<(N + 3) / 4, 256, 0, stream>>>(col, rs, cnt, g, dinv, b1, x1, N);
    k_gemm2<<<gN256, 256, 0, stream>>>(x1, W2, dinv, g2, N);
    k_gather2<<<(N + 3) / 4, 256, 0, stream>>>(col, rs, cnt, g2, dinv, b2, outp, N);
}

// Round 3
// 853.768 us; speedup vs baseline: 1.5349x; 1.1865x over previous
//
#include <hip/hip_runtime.h>
#include <math.h>

// Problem constants (reference: N_NODES=50000, F_in=1433, F1=16, F2=7)
#define F_IN 1433
#define F1 16
#define F2 7
#define SCAN_CHUNK 2048
#define G1_ROWS_PER_BLOCK 1024   // 256 threads x TM=4 rows

// ---------------- init ----------------
__global__ void k_init_cnt(int* __restrict__ cnt, int N) {
    int i = blockIdx.x * 256 + threadIdx.x;
    if (i < N) cnt[i] = 0;
}

// ---------------- degree count ----------------
__global__ void k_count(const int* __restrict__ edges, int* __restrict__ cnt, int E) {
    int e = blockIdx.x * 256 + threadIdx.x;
    if (e < E) atomicAdd(&cnt[edges[E + e]], 1);   // dst = edges[E + e]
}

// ---------------- scan (3-phase exclusive prefix over cnt -> row_start) ------
__global__ void k_scan1(const int* __restrict__ cnt, int* __restrict__ rs,
                        int* __restrict__ bsum, int N) {
    __shared__ int sh[256];
    int tid = threadIdx.x;
    int base = blockIdx.x * SCAN_CHUNK + tid * 8;
    int v[8];
    int s = 0;
#pragma unroll
    for (int u = 0; u < 8; ++u) {
        int idx = base + u;
        v[u] = (idx < N) ? cnt[idx] : 0;
        s += v[u];
    }
    sh[tid] = s;
    __syncthreads();
    for (int off = 1; off < 256; off <<= 1) {
        int y = 0;
        if (tid >= off) y = sh[tid - off];
        __syncthreads();
        sh[tid] += y;
        __syncthreads();
    }
    int run = sh[tid] - s;
#pragma unroll
    for (int u = 0; u < 8; ++u) {
        int idx = base + u;
        if (idx < N) rs[idx] = run;
        run += v[u];
    }
    if (tid == 255) bsum[blockIdx.x] = sh[255];
}

__global__ void k_scan2(const int* __restrict__ bsum, int* __restrict__ boff, int NB) {
    if (blockIdx.x == 0 && threadIdx.x == 0) {
        int r = 0;
        for (int b = 0; b < NB; ++b) { int t = bsum[b]; boff[b] = r; r += t; }
    }
}

__global__ void k_scan3(int* __restrict__ rs, int* __restrict__ cursor,
                        const int* __restrict__ cnt, float* __restrict__ dinv,
                        const int* __restrict__ boff, int N) {
    int i = blockIdx.x * 256 + threadIdx.x;
    if (i < N) {
        int r = rs[i] + boff[i / SCAN_CHUNK];
        rs[i] = r;
        cursor[i] = r;
        dinv[i] = rsqrtf((float)cnt[i] + 1.0f);   // +1 self loop
    }
}

// ---------------- CSR fill ----------------
__global__ void k_fill(const int* __restrict__ edges, int* __restrict__ cursor,
                       int* __restrict__ col, int E) {
    int e = blockIdx.x * 256 + threadIdx.x;
    if (e < E) {
        int d = edges[E + e];
        int s = edges[e];
        int pos = atomicAdd(&cursor[d], 1);
        col[pos] = s;
    }
}

// ---------------- GEMM1 split-K, W in LDS (broadcast), x transposed in LDS ---
// block = 256 threads, 1024 rows/block (4 rows/thread), KSEG k per segment.
template <int KSEG>
__global__ __launch_bounds__(256) void k_gemm1t(const float* __restrict__ x,
                                                const float* __restrict__ W,
                                                float* __restrict__ gpart, int N) {
    __shared__ float xs[8 * 1024];      // [kc][row], transposed, stride 1024
    __shared__ float wlds[KSEG * 16];   // W segment, row-major
    const int tid = threadIdx.x;
    const int r0 = blockIdx.x * G1_ROWS_PER_BLOCK;
    const int seg = blockIdx.y;
    const int ks0 = seg * KSEG;

    // stage W segment once (zero-padded past F_IN); coalesced
    for (int i = tid; i < KSEG * 16; i += 256) {
        int ks = ks0 + (i >> 4);
        wlds[i] = (ks < F_IN) ? W[(long)ks * 16 + (i & 15)] : 0.f;
    }

    float acc[4][16];
#pragma unroll
    for (int r = 0; r < 4; ++r)
#pragma unroll
        for (int j = 0; j < 16; ++j) acc[r][j] = 0.f;

    const int khalf = (tid & 1) * 4;   // staging: k sub-offset 0 or 4
    const int rstg  = tid >> 1;        // staging: row 0..127 (+p*128)

#pragma unroll 1
    for (int c0 = 0; c0 < KSEG; c0 += 8) {
        __syncthreads();
        // stage 1024 rows x 8 k, transposed into xs[k][row]
        const int kg = ks0 + c0 + khalf;
#pragma unroll
        for (int p = 0; p < 8; ++p) {
            int rl = p * 128 + rstg;
            int gr = r0 + rl;
            float4 v = make_float4(0.f, 0.f, 0.f, 0.f);
            if (gr < N) {
                const float* xr = x + (long)gr * F_IN + kg;
                if (kg + 3 < F_IN) v = *(const float4*)xr;
                else {
                    if (kg     < F_IN) v.x = xr[0];
                    if (kg + 1 < F_IN) v.y = xr[1];
                    if (kg + 2 < F_IN) v.z = xr[2];
                    if (kg + 3 < F_IN) v.w = xr[3];
                }
            }
            xs[(khalf + 0) * 1024 + rl] = v.x;
            xs[(khalf + 1) * 1024 + rl] = v.y;
            xs[(khalf + 2) * 1024 + rl] = v.z;
            xs[(khalf + 3) * 1024 + rl] = v.w;
        }
        __syncthreads();
#pragma unroll
        for (int kk = 0; kk < 8; ++kk) {
            float4 xv = *(const float4*)&xs[kk * 1024 + tid * 4];  // 4 rows
            const float4* wr = (const float4*)&wlds[(c0 + kk) * 16]; // broadcast
            float4 w0 = wr[0], w1 = wr[1], w2 = wr[2], w3 = wr[3];
            float xa[4] = {xv.x, xv.y, xv.z, xv.w};
#pragma unroll
            for (int r = 0; r < 4; ++r) {
                float xr = xa[r];
                acc[r][0]  = fmaf(xr, w0.x, acc[r][0]);
                acc[r][1]  = fmaf(xr, w0.y, acc[r][1]);
                acc[r][2]  = fmaf(xr, w0.z, acc[r][2]);
                acc[r][3]  = fmaf(xr, w0.w, acc[r][3]);
                acc[r][4]  = fmaf(xr, w1.x, acc[r][4]);
                acc[r][5]  = fmaf(xr, w1.y, acc[r][5]);
                acc[r][6]  = fmaf(xr, w1.z, acc[r][6]);
                acc[r][7]  = fmaf(xr, w1.w, acc[r][7]);
                acc[r][8]  = fmaf(xr, w2.x, acc[r][8]);
                acc[r][9]  = fmaf(xr, w2.y, acc[r][9]);
                acc[r][10] = fmaf(xr, w2.z, acc[r][10]);
                acc[r][11] = fmaf(xr, w2.w, acc[r][11]);
                acc[r][12] = fmaf(xr, w3.x, acc[r][12]);
                acc[r][13] = fmaf(xr, w3.y, acc[r][13]);
                acc[r][14] = fmaf(xr, w3.z, acc[r][14]);
                acc[r][15] = fmaf(xr, w3.w, acc[r][15]);
            }
        }
    }

#pragma unroll
    for (int r = 0; r < 4; ++r) {
        int row = r0 + tid * 4 + r;
        if (row < N) {
            float4* out = (float4*)&gpart[((long)seg * N + row) * 16];
            out[0] = make_float4(acc[r][0],  acc[r][1],  acc[r][2],  acc[r][3]);
            out[1] = make_float4(acc[r][4],  acc[r][5],  acc[r][6],  acc[r][7]);
            out[2] = make_float4(acc[r][8],  acc[r][9],  acc[r][10], acc[r][11]);
            out[3] = make_float4(acc[r][12], acc[r][13], acc[r][14], acc[r][15]);
        }
    }
}

// ---------------- reduce partials: g = dinv[row] * sum_seg gpart -------------
__global__ __launch_bounds__(256) void k_greduce(const float* __restrict__ gpart,
                                                 const float* __restrict__ dinv,
                                                 float* __restrict__ g, int N, int nseg) {
    int i4 = blockIdx.x * 256 + threadIdx.x;   // index over N*4 float4s
    if (i4 >= N * 4) return;
    const float4* gp = (const float4*)gpart;
    float4 s = gp[i4];
    for (int p = 1; p < nseg; ++p) {
        float4 t = gp[(long)p * N * 4 + i4];
        s.x += t.x; s.y += t.y; s.z += t.z; s.w += t.w;
    }
    float d = dinv[i4 >> 2];
    s.x *= d; s.y *= d; s.z *= d; s.w *= d;
    ((float4*)g)[i4] = s;
}

// ---------------- gather layer1: x1 = relu(dinv*(sum g[src] + g[self]) + b1) --
__global__ __launch_bounds__(256) void k_gather1(const int* __restrict__ col,
                                                 const int* __restrict__ rs,
                                                 const int* __restrict__ cnt,
                                                 const float* __restrict__ g,
                                                 const float* __restrict__ dinv,
                                                 const float* __restrict__ b1,
                                                 float* __restrict__ x1, int N) {
    int node = blockIdx.x * 4 + (threadIdx.x >> 6);
    if (node >= N) return;
    int lane = threadIdx.x & 63;
    int q = lane >> 4;   // neighbor slot 0..3
    int j = lane & 15;   // feature
    int start = rs[node];
    int c = cnt[node];
    float acc = 0.f;
    for (int p = q; p < c; p += 4) {
        int s = col[start + p];
        acc += g[(long)s * F1 + j];
    }
    acc += __shfl_down(acc, 32, 64);
    acc += __shfl_down(acc, 16, 64);
    if (lane < 16) {
        float v = dinv[node] * (acc + g[(long)node * F1 + j]) + b1[j];
        x1[(long)node * F1 + j] = fmaxf(v, 0.f);
    }
}

// ---------------- GEMM2: g2 = dinv * (x1 @ W2), padded to 8 cols -------------
__global__ __launch_bounds__(256) void k_gemm2(const float* __restrict__ x1,
                                               const float* __restrict__ W2,
                                               const float* __restrict__ dinv,
                                               float* __restrict__ g2, int N) {
    int i = blockIdx.x * 256 + threadIdx.x;
    if (i >= N) return;
    const float4* xr = (const float4*)(x1 + (long)i * F1);
    float4 a0 = xr[0], a1 = xr[1], a2 = xr[2], a3 = xr[3];
    float xv[F1] = {a0.x, a0.y, a0.z, a0.w, a1.x, a1.y, a1.z, a1.w,
                    a2.x, a2.y, a2.z, a2.w, a3.x, a3.y, a3.z, a3.w};
    float acc[F2];
#pragma unroll
    for (int j = 0; j < F2; ++j) acc[j] = 0.f;
#pragma unroll
    for (int k = 0; k < F1; ++k) {
#pragma unroll
        for (int j = 0; j < F2; ++j) acc[j] = fmaf(xv[k], W2[k * F2 + j], acc[j]);
    }
    float d = dinv[i];
    float4* out = (float4*)(g2 + (long)i * 8);
    out[0] = make_float4(d * acc[0], d * acc[1], d * acc[2], d * acc[3]);
    out[1] = make_float4(d * acc[4], d * acc[5], d * acc[6], 0.f);
}

// ---------------- gather layer2 + bias + log_softmax -> d_out ----------------
__global__ __launch_bounds__(256) void k_gather2(const int* __restrict__ col,
                                                 const int* __restrict__ rs,
                                                 const int* __restrict__ cnt,
                                                 const float* __restrict__ g2,
                                                 const float* __restrict__ dinv,
                                                 const float* __restrict__ b2,
                                                 float* __restrict__ out, int N) {
    int node = blockIdx.x * 4 + (threadIdx.x >> 6);
    if (node >= N) return;
    int lane = threadIdx.x & 63;
    int q = lane >> 3;  // neighbor slot 0..7
    int j = lane & 7;   // feature 0..7 (7 = pad)
    int start = rs[node];
    int c = cnt[node];
    float acc = 0.f;
    for (int p = q; p < c; p += 8) {
        int s = col[start + p];
        acc += g2[(long)s * 8 + j];
    }
    acc += __shfl_down(acc, 32, 64);
    acc += __shfl_down(acc, 16, 64);
    acc += __shfl_down(acc, 8, 64);
    if (lane < 8) {
        float vv = -INFINITY;
        if (j < F2)
            vv = dinv[node] * (acc + g2[(long)node * 8 + j]) + b2[j];
        float m = vv;
        m = fmaxf(m, __shfl_xor(m, 1, 64));
        m = fmaxf(m, __shfl_xor(m, 2, 64));
        m = fmaxf(m, __shfl_xor(m, 4, 64));
        float e = (j < F2) ? expf(vv - m) : 0.f;
        e += __shfl_xor(e, 1, 64);
        e += __shfl_xor(e, 2, 64);
        e += __shfl_xor(e, 4, 64);
        if (j < F2)
            out[(long)node * F2 + j] = vv - m - logf(e);
    }
}

extern "C" void kernel_launch(void* const* d_in, const int* in_sizes, int n_in,
                              void* d_out, int out_size, void* d_ws, size_t ws_size,
                              hipStream_t stream) {
    const float* x     = (const float*)d_in[0];
    const int*   edges = (const int*)d_in[1];
    const float* W1    = (const float*)d_in[2];
    const float* b1    = (const float*)d_in[3];
    const float* W2    = (const float*)d_in[4];
    const float* b2    = (const float*)d_in[5];
    float* outp = (float*)d_out;

    int N = in_sizes[0] / F_IN;       // 50000
    int E = in_sizes[1] / 2;          // 1600000
    int NB = (N + SCAN_CHUNK - 1) / SCAN_CHUNK;

    char* ws = (char*)d_ws;
    size_t o = 0;
    auto alloc = [&](size_t bytes) { size_t r = o; o += (bytes + 255) & ~(size_t)255; return r; };
    int*   cnt    = (int*)  (ws + alloc((size_t)N * 4));
    int*   rs     = (int*)  (ws + alloc((size_t)N * 4));
    int*   cursor = (int*)  (ws + alloc((size_t)N * 4));
    float* dinv   = (float*)(ws + alloc((size_t)N * 4));
    int*   bsum   = (int*)  (ws + alloc((size_t)NB * 4));
    int*   boff   = (int*)  (ws + alloc((size_t)NB * 4));
    int*   col    = (int*)  (ws + alloc((size_t)E * 4));
    float* g      = (float*)(ws + alloc((size_t)N * F1 * 4));
    float* x1     = (float*)(ws + alloc((size_t)N * F1 * 4));
    float* g2     = (float*)(ws + alloc((size_t)N * 8 * 4));
    // choose split-K factor by available workspace (ws_size is call-invariant,
    // so the launch sequence is identical every call — graph-capture safe)
    size_t fixed = o;
    int nseg = (fixed + (size_t)18 * N * F1 * 4 <= ws_size) ? 18 : 9;
    float* gpart  = (float*)(ws + alloc((size_t)nseg * N * F1 * 4));
    (void)n_in; (void)out_size;

    int gN256 = (N + 255) / 256;
    int gE256 = (E + 255) / 256;

    k_init_cnt<<<gN256, 256, 0, stream>>>(cnt, N);
    k_count<<<gE256, 256, 0, stream>>>(edges, cnt, E);
    k_scan1<<<NB, 256, 0, stream>>>(cnt, rs, bsum, N);
    k_scan2<<<1, 64, 0, stream>>>(bsum, boff, NB);
    k_scan3<<<gN256, 256, 0, stream>>>(rs, cursor, cnt, dinv, boff, N);
    k_fill<<<gE256, 256, 0, stream>>>(edges, cursor, col, E);

    dim3 g1grid((N + G1_ROWS_PER_BLOCK - 1) / G1_ROWS_PER_BLOCK, nseg);
    if (nseg == 18)
        k_gemm1t<80><<<g1grid, 256, 0, stream>>>(x, W1, gpart, N);
    else
        k_gemm1t<160><<<g1grid, 256, 0, stream>>>(x, W1, gpart, N);
    k_greduce<<<(N * 4 + 255) / 256, 256, 0, stream>>>(gpart, dinv, g, N, nseg);
    k_gather1<<<(N + 3) / 4, 256, 0, stream>>>(col, rs, cnt, g, dinv, b1, x1, N);
    k_gemm2<<<gN256, 256, 0, stream>>>(x1, W2, dinv, g2, N);
    k_gather2<<<(N + 3) / 4, 256, 0, stream>>>(col, rs, cnt, g2, dinv, b2, outp, N);
}

// Round 4
// 829.392 us; speedup vs baseline: 1.5800x; 1.0294x over previous
//
#include <hip/hip_runtime.h>
#include <math.h>

// Problem constants (reference: N_NODES=50000, F_in=1433, F1=16, F2=7)
#define F_IN 1433
#define F1 16
#define F2 7
#define SCAN_CHUNK 2048
#define NREP 8          // atomic-contention replication factor
#define KSEG 64         // K per split-K segment (readlane kernel: 64 = wave size)
#define KC 16           // K staged per LDS chunk

// ---------------- init (zeros replicated counters) ----------------
__global__ void k_init_cnt(int* __restrict__ cnt_r, int n) {
    int i = blockIdx.x * 256 + threadIdx.x;
    if (i < n) cnt_r[i] = 0;
}

// ---------------- degree count, 8-way replicated ----------------
__global__ void k_count(const int* __restrict__ edges, int* __restrict__ cnt_r,
                        int E, int N) {
    int e = blockIdx.x * 256 + threadIdx.x;
    if (e < E) atomicAdd(&cnt_r[(blockIdx.x & (NREP - 1)) * N + edges[E + e]], 1);
}

// ---------------- scan (3-phase exclusive prefix over summed cnt -> rs) ------
__global__ void k_scan1(const int* __restrict__ cnt_r, int* __restrict__ rs,
                        int* __restrict__ bsum, int N) {
    __shared__ int sh[256];
    int tid = threadIdx.x;
    int base = blockIdx.x * SCAN_CHUNK + tid * 8;
    int v[8];
    int s = 0;
#pragma unroll
    for (int u = 0; u < 8; ++u) {
        int idx = base + u;
        int t = 0;
        if (idx < N) {
#pragma unroll
            for (int r = 0; r < NREP; ++r) t += cnt_r[r * N + idx];
        }
        v[u] = t;
        s += t;
    }
    sh[tid] = s;
    __syncthreads();
    for (int off = 1; off < 256; off <<= 1) {
        int y = 0;
        if (tid >= off) y = sh[tid - off];
        __syncthreads();
        sh[tid] += y;
        __syncthreads();
    }
    int run = sh[tid] - s;
#pragma unroll
    for (int u = 0; u < 8; ++u) {
        int idx = base + u;
        if (idx < N) rs[idx] = run;
        run += v[u];
    }
    if (tid == 255) bsum[blockIdx.x] = sh[255];
}

__global__ void k_scan2(const int* __restrict__ bsum, int* __restrict__ boff, int NB) {
    if (blockIdx.x == 0 && threadIdx.x == 0) {
        int r = 0;
        for (int b = 0; b < NB; ++b) { int t = bsum[b]; boff[b] = r; r += t; }
    }
}

// finalize rs, build per-replica cursors, total cnt, dinv
__global__ void k_scan3(int* __restrict__ rs, int* __restrict__ cursor_r,
                        const int* __restrict__ cnt_r, int* __restrict__ cnt,
                        float* __restrict__ dinv, const int* __restrict__ boff, int N) {
    int i = blockIdx.x * 256 + threadIdx.x;
    if (i < N) {
        int run = rs[i] + boff[i / SCAN_CHUNK];
        rs[i] = run;
        int total = 0;
#pragma unroll
        for (int r = 0; r < NREP; ++r) {
            cursor_r[r * N + i] = run;
            int c = cnt_r[r * N + i];
            run += c;
            total += c;
        }
        cnt[i] = total;
        dinv[i] = rsqrtf((float)total + 1.0f);   // +1 self loop
    }
}

// ---------------- CSR fill (replica matches k_count's: same e -> same block) -
__global__ void k_fill(const int* __restrict__ edges, int* __restrict__ cursor_r,
                       int* __restrict__ col, int E, int N) {
    int e = blockIdx.x * 256 + threadIdx.x;
    if (e < E) {
        int d = edges[E + e];
        int s = edges[e];
        int pos = atomicAdd(&cursor_r[(blockIdx.x & (NREP - 1)) * N + d], 1);
        col[pos] = s;
    }
}

// ---------------- GEMM1 split-K, W via v_readlane (no LDS W traffic) ---------
// block = 256 threads, 1024 rows/block, KSEG=64 k per segment.
// wreg[j] (lane l) = W[ks0 + l][j]; W[ks0+k][j] = readlane(wreg[j], k).
__global__ __launch_bounds__(256) void k_gemm1r(const float* __restrict__ x,
                                                const float* __restrict__ W,
                                                float* __restrict__ gpart, int N) {
    __shared__ float xs[KC * 1024];     // [plane 0..15][row 0..1023], XOR-swizzled
    const int tid = threadIdx.x;
    const int lane = tid & 63;
    const int r0 = blockIdx.x * 1024;
    const int seg = blockIdx.y;
    const int ks0 = seg * KSEG;

    // preload W rows ks0..ks0+63 across lanes (zero past F_IN)
    float wreg[16];
    {
        int krow = ks0 + lane;
        if (krow < F_IN) {
            const float4* wr = (const float4*)(W + (long)krow * 16);
            float4 a = wr[0], b = wr[1], c = wr[2], d = wr[3];
            wreg[0] = a.x;  wreg[1] = a.y;  wreg[2] = a.z;  wreg[3] = a.w;
            wreg[4] = b.x;  wreg[5] = b.y;  wreg[6] = b.z;  wreg[7] = b.w;
            wreg[8] = c.x;  wreg[9] = c.y;  wreg[10] = c.z; wreg[11] = c.w;
            wreg[12] = d.x; wreg[13] = d.y; wreg[14] = d.z; wreg[15] = d.w;
        } else {
#pragma unroll
            for (int j = 0; j < 16; ++j) wreg[j] = 0.f;
        }
    }

    float acc[4][16];
#pragma unroll
    for (int r = 0; r < 4; ++r)
#pragma unroll
        for (int j = 0; j < 16; ++j) acc[r][j] = 0.f;

    const int kf = (tid & 3) * 4;   // staging k sub-offset (0,4,8,12)
    const int rsub = tid >> 2;      // staging row within 64-row step

#pragma unroll 1
    for (int c0 = 0; c0 < KSEG; c0 += KC) {
        __syncthreads();
        const int kg = ks0 + c0 + kf;
#pragma unroll
        for (int p = 0; p < 16; ++p) {
            int rl = p * 64 + rsub;
            int gr = r0 + rl;
            float4 v = make_float4(0.f, 0.f, 0.f, 0.f);
            if (gr < N) {
                const float* xr = x + (long)gr * F_IN + kg;
                if (kg + 3 < F_IN) v = *(const float4*)xr;
                else {
                    if (kg     < F_IN) v.x = xr[0];
                    if (kg + 1 < F_IN) v.y = xr[1];
                    if (kg + 2 < F_IN) v.z = xr[2];
                }
            }
            int grp = rl >> 2, off = rl & 3;
            // transposed, group-XOR-swizzled store (write conflicts <= 2-way)
            xs[(kf + 0) * 1024 + ((grp ^ ((kf + 0) & 7)) << 2) + off] = v.x;
            xs[(kf + 1) * 1024 + ((grp ^ ((kf + 1) & 7)) << 2) + off] = v.y;
            xs[(kf + 2) * 1024 + ((grp ^ ((kf + 2) & 7)) << 2) + off] = v.z;
            xs[(kf + 3) * 1024 + ((grp ^ ((kf + 3) & 7)) << 2) + off] = v.w;
        }
        __syncthreads();
#pragma unroll
        for (int kk = 0; kk < KC; ++kk) {
            float w[16];
#pragma unroll
            for (int j = 0; j < 16; ++j)
                w[j] = __int_as_float(
                    __builtin_amdgcn_readlane(__float_as_int(wreg[j]), c0 + kk));
            const float4 xv = *(const float4*)&xs[kk * 1024 + ((tid ^ (kk & 7)) << 2)];
            const float xa[4] = {xv.x, xv.y, xv.z, xv.w};
#pragma unroll
            for (int r = 0; r < 4; ++r)
#pragma unroll
                for (int j = 0; j < 16; ++j)
                    acc[r][j] = fmaf(xa[r], w[j], acc[r][j]);
        }
    }

#pragma unroll
    for (int r = 0; r < 4; ++r) {
        int row = r0 + tid * 4 + r;
        if (row < N) {
            float4* o = (float4*)&gpart[((long)seg * N + row) * 16];
            o[0] = make_float4(acc[r][0],  acc[r][1],  acc[r][2],  acc[r][3]);
            o[1] = make_float4(acc[r][4],  acc[r][5],  acc[r][6],  acc[r][7]);
            o[2] = make_float4(acc[r][8],  acc[r][9],  acc[r][10], acc[r][11]);
            o[3] = make_float4(acc[r][12], acc[r][13], acc[r][14], acc[r][15]);
        }
    }
}

// ---------------- fallback GEMM1 (round-3 structure), if ws too small --------
template <int KSEGT>
__global__ __launch_bounds__(256) void k_gemm1t(const float* __restrict__ x,
                                                const float* __restrict__ W,
                                                float* __restrict__ gpart, int N) {
    __shared__ float xs[8 * 1024];
    __shared__ float wlds[KSEGT * 16];
    const int tid = threadIdx.x;
    const int r0 = blockIdx.x * 1024;
    const int seg = blockIdx.y;
    const int ks0 = seg * KSEGT;
    for (int i = tid; i < KSEGT * 16; i += 256) {
        int ks = ks0 + (i >> 4);
        wlds[i] = (ks < F_IN) ? W[(long)ks * 16 + (i & 15)] : 0.f;
    }
    float acc[4][16];
#pragma unroll
    for (int r = 0; r < 4; ++r)
#pragma unroll
        for (int j = 0; j < 16; ++j) acc[r][j] = 0.f;
    const int khalf = (tid & 1) * 4;
    const int rstg  = tid >> 1;
#pragma unroll 1
    for (int c0 = 0; c0 < KSEGT; c0 += 8) {
        __syncthreads();
        const int kg = ks0 + c0 + khalf;
#pragma unroll
        for (int p = 0; p < 8; ++p) {
            int rl = p * 128 + rstg;
            int gr = r0 + rl;
            float4 v = make_float4(0.f, 0.f, 0.f, 0.f);
            if (gr < N) {
                const float* xr = x + (long)gr * F_IN + kg;
                if (kg + 3 < F_IN) v = *(const float4*)xr;
                else {
                    if (kg     < F_IN) v.x = xr[0];
                    if (kg + 1 < F_IN) v.y = xr[1];
                    if (kg + 2 < F_IN) v.z = xr[2];
                }
            }
            xs[(khalf + 0) * 1024 + rl] = v.x;
            xs[(khalf + 1) * 1024 + rl] = v.y;
            xs[(khalf + 2) * 1024 + rl] = v.z;
            xs[(khalf + 3) * 1024 + rl] = v.w;
        }
        __syncthreads();
#pragma unroll
        for (int kk = 0; kk < 8; ++kk) {
            float4 xv = *(const float4*)&xs[kk * 1024 + tid * 4];
            const float4* wr = (const float4*)&wlds[(c0 + kk) * 16];
            float4 w0 = wr[0], w1 = wr[1], w2 = wr[2], w3 = wr[3];
            float xa[4] = {xv.x, xv.y, xv.z, xv.w};
#pragma unroll
            for (int r = 0; r < 4; ++r) {
                float xr = xa[r];
                acc[r][0]  = fmaf(xr, w0.x, acc[r][0]);
                acc[r][1]  = fmaf(xr, w0.y, acc[r][1]);
                acc[r][2]  = fmaf(xr, w0.z, acc[r][2]);
                acc[r][3]  = fmaf(xr, w0.w, acc[r][3]);
                acc[r][4]  = fmaf(xr, w1.x, acc[r][4]);
                acc[r][5]  = fmaf(xr, w1.y, acc[r][5]);
                acc[r][6]  = fmaf(xr, w1.z, acc[r][6]);
                acc[r][7]  = fmaf(xr, w1.w, acc[r][7]);
                acc[r][8]  = fmaf(xr, w2.x, acc[r][8]);
                acc[r][9]  = fmaf(xr, w2.y, acc[r][9]);
                acc[r][10] = fmaf(xr, w2.z, acc[r][10]);
                acc[r][11] = fmaf(xr, w2.w, acc[r][11]);
                acc[r][12] = fmaf(xr, w3.x, acc[r][12]);
                acc[r][13] = fmaf(xr, w3.y, acc[r][13]);
                acc[r][14] = fmaf(xr, w3.z, acc[r][14]);
                acc[r][15] = fmaf(xr, w3.w, acc[r][15]);
            }
        }
    }
#pragma unroll
    for (int r = 0; r < 4; ++r) {
        int row = r0 + tid * 4 + r;
        if (row < N) {
            float4* out = (float4*)&gpart[((long)seg * N + row) * 16];
            out[0] = make_float4(acc[r][0],  acc[r][1],  acc[r][2],  acc[r][3]);
            out[1] = make_float4(acc[r][4],  acc[r][5],  acc[r][6],  acc[r][7]);
            out[2] = make_float4(acc[r][8],  acc[r][9],  acc[r][10], acc[r][11]);
            out[3] = make_float4(acc[r][12], acc[r][13], acc[r][14], acc[r][15]);
        }
    }
}

// ---------------- reduce partials: g = dinv[row] * sum_seg gpart -------------
__global__ __launch_bounds__(256) void k_greduce(const float* __restrict__ gpart,
                                                 const float* __restrict__ dinv,
                                                 float* __restrict__ g, int N, int nseg) {
    int i4 = blockIdx.x * 256 + threadIdx.x;
    if (i4 >= N * 4) return;
    const float4* gp = (const float4*)gpart;
    float4 s = gp[i4];
    for (int p = 1; p < nseg; ++p) {
        float4 t = gp[(long)p * N * 4 + i4];
        s.x += t.x; s.y += t.y; s.z += t.z; s.w += t.w;
    }
    float d = dinv[i4 >> 2];
    s.x *= d; s.y *= d; s.z *= d; s.w *= d;
    ((float4*)g)[i4] = s;
}

// ---------------- gather layer1: x1 = relu(dinv*(sum g[src] + g[self]) + b1) --
__global__ __launch_bounds__(256) void k_gather1(const int* __restrict__ col,
                                                 const int* __restrict__ rs,
                                                 const int* __restrict__ cnt,
                                                 const float* __restrict__ g,
                                                 const float* __restrict__ dinv,
                                                 const float* __restrict__ b1,
                                                 float* __restrict__ x1, int N) {
    int node = blockIdx.x * 4 + (threadIdx.x >> 6);
    if (node >= N) return;
    int lane = threadIdx.x & 63;
    int q = lane >> 4;   // neighbor slot 0..3
    int j = lane & 15;   // feature
    int start = rs[node];
    int c = cnt[node];
    float acc = 0.f;
    for (int p = q; p < c; p += 4) {
        int s = col[start + p];
        acc += g[(long)s * F1 + j];
    }
    acc += __shfl_down(acc, 32, 64);
    acc += __shfl_down(acc, 16, 64);
    if (lane < 16) {
        float v = dinv[node] * (acc + g[(long)node * F1 + j]) + b1[j];
        x1[(long)node * F1 + j] = fmaxf(v, 0.f);
    }
}

// ---------------- GEMM2: g2 = dinv * (x1 @ W2), padded to 8 cols -------------
__global__ __launch_bounds__(256) void k_gemm2(const float* __restrict__ x1,
                                               const float* __restrict__ W2,
                                               const float* __restrict__ dinv,
                                               float* __restrict__ g2, int N) {
    int i = blockIdx.x * 256 + threadIdx.x;
    if (i >= N) return;
    const float4* xr = (const float4*)(x1 + (long)i * F1);
    float4 a0 = xr[0], a1 = xr[1], a2 = xr[2], a3 = xr[3];
    float xv[F1] = {a0.x, a0.y, a0.z, a0.w, a1.x, a1.y, a1.z, a1.w,
                    a2.x, a2.y, a2.z, a2.w, a3.x, a3.y, a3.z, a3.w};
    float acc[F2];
#pragma unroll
    for (int j = 0; j < F2; ++j) acc[j] = 0.f;
#pragma unroll
    for (int k = 0; k < F1; ++k) {
#pragma unroll
        for (int j = 0; j < F2; ++j) acc[j] = fmaf(xv[k], W2[k * F2 + j], acc[j]);
    }
    float d = dinv[i];
    float4* out = (float4*)(g2 + (long)i * 8);
    out[0] = make_float4(d * acc[0], d * acc[1], d * acc[2], d * acc[3]);
    out[1] = make_float4(d * acc[4], d * acc[5], d * acc[6], 0.f);
}

// ---------------- gather layer2 + bias + log_softmax -> d_out ----------------
__global__ __launch_bounds__(256) void k_gather2(const int* __restrict__ col,
                                                 const int* __restrict__ rs,
                                                 const int* __restrict__ cnt,
                                                 const float* __restrict__ g2,
                                                 const float* __restrict__ dinv,
                                                 const float* __restrict__ b2,
                                                 float* __restrict__ out, int N) {
    int node = blockIdx.x * 4 + (threadIdx.x >> 6);
    if (node >= N) return;
    int lane = threadIdx.x & 63;
    int q = lane >> 3;  // neighbor slot 0..7
    int j = lane & 7;   // feature 0..7 (7 = pad)
    int start = rs[node];
    int c = cnt[node];
    float acc = 0.f;
    for (int p = q; p < c; p += 8) {
        int s = col[start + p];
        acc += g2[(long)s * 8 + j];
    }
    acc += __shfl_down(acc, 32, 64);
    acc += __shfl_down(acc, 16, 64);
    acc += __shfl_down(acc, 8, 64);
    if (lane < 8) {
        float vv = -INFINITY;
        if (j < F2)
            vv = dinv[node] * (acc + g2[(long)node * 8 + j]) + b2[j];
        float m = vv;
        m = fmaxf(m, __shfl_xor(m, 1, 64));
        m = fmaxf(m, __shfl_xor(m, 2, 64));
        m = fmaxf(m, __shfl_xor(m, 4, 64));
        float e = (j < F2) ? expf(vv - m) : 0.f;
        e += __shfl_xor(e, 1, 64);
        e += __shfl_xor(e, 2, 64);
        e += __shfl_xor(e, 4, 64);
        if (j < F2)
            out[(long)node * F2 + j] = vv - m - logf(e);
    }
}

extern "C" void kernel_launch(void* const* d_in, const int* in_sizes, int n_in,
                              void* d_out, int out_size, void* d_ws, size_t ws_size,
                              hipStream_t stream) {
    const float* x     = (const float*)d_in[0];
    const int*   edges = (const int*)d_in[1];
    const float* W1    = (const float*)d_in[2];
    const float* b1    = (const float*)d_in[3];
    const float* W2    = (const float*)d_in[4];
    const float* b2    = (const float*)d_in[5];
    float* outp = (float*)d_out;

    int N = in_sizes[0] / F_IN;       // 50000
    int E = in_sizes[1] / 2;          // 1600000
    int NB = (N + SCAN_CHUNK - 1) / SCAN_CHUNK;

    char* ws = (char*)d_ws;
    size_t o = 0;
    auto alloc = [&](size_t bytes) { size_t r = o; o += (bytes + 255) & ~(size_t)255; return r; };
    int*   cnt_r    = (int*)  (ws + alloc((size_t)NREP * N * 4));
    int*   cursor_r = (int*)  (ws + alloc((size_t)NREP * N * 4));
    int*   cnt      = (int*)  (ws + alloc((size_t)N * 4));
    int*   rs       = (int*)  (ws + alloc((size_t)N * 4));
    float* dinv     = (float*)(ws + alloc((size_t)N * 4));
    int*   bsum     = (int*)  (ws + alloc((size_t)NB * 4));
    int*   boff     = (int*)  (ws + alloc((size_t)NB * 4));
    int*   col      = (int*)  (ws + alloc((size_t)E * 4));
    float* g        = (float*)(ws + alloc((size_t)N * F1 * 4));
    float* x1       = (float*)(ws + alloc((size_t)N * F1 * 4));
    float* g2       = (float*)(ws + alloc((size_t)N * 8 * 4));
    size_t fixed = o;
    // pick gemm1 variant by workspace capacity (ws_size is call-invariant ->
    // identical launch sequence each call; graph-capture safe)
    int nseg23 = (F_IN + KSEG - 1) / KSEG;                 // 23
    int path;   // 0 = readlane KSEG=64, 1 = fallback t<80>, 2 = fallback t<160>
    int nseg;
    if (fixed + (size_t)nseg23 * N * F1 * 4 <= ws_size) { path = 0; nseg = nseg23; }
    else if (fixed + (size_t)18 * N * F1 * 4 <= ws_size) { path = 1; nseg = 18; }
    else                                                  { path = 2; nseg = 9;  }
    float* gpart = (float*)(ws + alloc((size_t)nseg * N * F1 * 4));
    (void)n_in; (void)out_size;

    int gN256 = (N + 255) / 256;
    int gE256 = (E + 255) / 256;

    k_init_cnt<<<(NREP * N + 255) / 256, 256, 0, stream>>>(cnt_r, NREP * N);
    k_count<<<gE256, 256, 0, stream>>>(edges, cnt_r, E, N);
    k_scan1<<<NB, 256, 0, stream>>>(cnt_r, rs, bsum, N);
    k_scan2<<<1, 64, 0, stream>>>(bsum, boff, NB);
    k_scan3<<<gN256, 256, 0, stream>>>(rs, cursor_r, cnt_r, cnt, dinv, boff, N);
    k_fill<<<gE256, 256, 0, stream>>>(edges, cursor_r, col, E, N);

    int rb = (N + 1023) / 1024;
    if (path == 0) {
        dim3 grd(rb, nseg);
        k_gemm1r<<<grd, 256, 0, stream>>>(x, W1, gpart, N);
    } else if (path == 1) {
        dim3 grd(rb, nseg);
        k_gemm1t<80><<<grd, 256, 0, stream>>>(x, W1, gpart, N);
    } else {
        dim3 grd(rb, nseg);
        k_gemm1t<160><<<grd, 256, 0, stream>>>(x, W1, gpart, N);
    }
    k_greduce<<<(N * 4 + 255) / 256, 256, 0, stream>>>(gpart, dinv, g, N, nseg);
    k_gather1<<<(N + 3) / 4, 256, 0, stream>>>(col, rs, cnt, g, dinv, b1, x1, N);
    k_gemm2<<<gN256, 256, 0, stream>>>(x1, W2, dinv, g2, N);
    k_gather2<<<(N + 3) / 4, 256, 0, stream>>>(col, rs, cnt, g2, dinv, b2, outp, N);
}